// Round 3
// baseline (4131.916 us; speedup 1.0000x reference)
//
#include <hip/hip_runtime.h>
#include <float.h>

#define N_VOX 32768
#define N_CODES 8192
#define DIM 64

// output float offsets (flat, in return order)
#define Q_OFF 0
#define VQ_OFF (N_VOX * DIM)      // 2097152
#define CM_OFF (VQ_OFF + 1)
#define IDX_OFF (VQ_OFF + 2)

// workspace float offsets
#define WS_ACC 0                      // float loss accumulator
#define WS_CNT 1                      // int completion counter
#define WS_ESQH 64                    // 8192 floats: ||e||^2 / 2
#define WS_EHI (WS_ESQH + N_CODES)    // 8256: hi-plane f16, fragment-ordered (1 MB)
#define WS_ELO (WS_EHI + N_CODES * DIM / 2)   // lo-plane f16 (1 MB)
// total ~2.13 MB < ws_size used previously

typedef _Float16 half8 __attribute__((ext_vector_type(8)));
typedef float floatx4 __attribute__((ext_vector_type(4)));

// ---------------------------------------------------------------- k_cvt
// Codebook -> hi/lo f16 planes stored in MFMA B-fragment order:
// half8 index = g*128 + kc*64 + n*4 + q   (g=row>>4, n=row&15, kc,q from chunk)
// so a wave's frag load (lane=(q,n)) is one contiguous, coalesced 1 KB.
__global__ __launch_bounds__(256) void k_cvt(const float* __restrict__ e,
                                             float* __restrict__ ws) {
  int gid = blockIdx.x * 256 + threadIdx.x;
  if (gid == 0) { ws[WS_ACC] = 0.f; ((int*)ws)[WS_CNT] = 0; }
  int row = gid >> 3, c = gid & 7;          // 8 chunks of 8 dims per row
  const float* src = e + (size_t)row * DIM + c * 8;
  float4 a = *(const float4*)src;
  float4 b = *(const float4*)(src + 4);
  float x[8] = {a.x, a.y, a.z, a.w, b.x, b.y, b.z, b.w};
  float s = 0.f;
  half8 hv, lv;
  #pragma unroll
  for (int j = 0; j < 8; ++j) {
    s += x[j] * x[j];                       // esq in fp32 from originals
    _Float16 h = (_Float16)x[j];
    hv[j] = h;
    lv[j] = (_Float16)(x[j] - (float)h);
  }
  s += __shfl_xor(s, 1); s += __shfl_xor(s, 2); s += __shfl_xor(s, 4);
  if (c == 0) ws[WS_ESQH + row] = 0.5f * s;
  int g = row >> 4, n = row & 15, kc = c >> 2, q = c & 3;
  size_t p = (size_t)g * 128 + kc * 64 + n * 4 + q;
  ((half8*)(ws + WS_EHI))[p] = hv;
  ((half8*)(ws + WS_ELO))[p] = lv;
}

// ---------------------------------------------------------------- k_argmin
// Block = 64 voxels, 4 waves; each wave: same 64 voxels (4 m-frags in regs)
// x its own 2048-code quarter. No LDS staging, no barriers in the K-loop:
// B-frags stream from L2-resident global planes with a 1-group prefetch.
// Surrogate t = esq/2 - dot (z_sq drops from argmin); 3-term split MFMA
// (hh + hl + lh; lo*lo ~ 2^-22 relative, negligible).
// Epilogue fused: loss via d2 = z_sq + 2*t_min, gather, indices, scalars.
__global__ __launch_bounds__(256, 2) void k_argmin(const float* __restrict__ z,
                                                   const float* __restrict__ e,
                                                   float* __restrict__ ws,
                                                   float* __restrict__ out) {
  __shared__ float sMval[4][64];
  __shared__ int   sMidx[4][64];
  __shared__ float sZsq[64];
  __shared__ int   sIdxF[64];

  const int tid  = threadIdx.x;
  const int lane = tid & 63;
  const int wave = tid >> 6;
  const int n16  = lane & 15;
  const int quad = lane >> 4;
  const int vb   = blockIdx.x * 64;
  const int wbase = wave * 2048;            // this wave's code range

  // ---- A fragments (4 m-frags x 2 k-chunks, hi/lo) + z_sq
  half8 ahi[4][2], alo[4][2];
  float zsq[4] = {0.f, 0.f, 0.f, 0.f};
  #pragma unroll
  for (int m = 0; m < 4; ++m)
    #pragma unroll
    for (int kc = 0; kc < 2; ++kc) {
      const float* src = z + (size_t)(vb + m * 16 + n16) * DIM + kc * 32 + quad * 8;
      float4 a = *(const float4*)src;
      float4 b = *(const float4*)(src + 4);
      float x[8] = {a.x, a.y, a.z, a.w, b.x, b.y, b.z, b.w};
      #pragma unroll
      for (int j = 0; j < 8; ++j) {
        zsq[m] += x[j] * x[j];
        _Float16 h = (_Float16)x[j];
        ahi[m][kc][j] = h;
        alo[m][kc][j] = (_Float16)(x[j] - (float)h);
      }
    }
  #pragma unroll
  for (int m = 0; m < 4; ++m) {             // reduce over quads (lanes ^16,^32)
    zsq[m] += __shfl_xor(zsq[m], 16);
    zsq[m] += __shfl_xor(zsq[m], 32);
  }
  if (wave == 0 && quad == 0)
    #pragma unroll
    for (int m = 0; m < 4; ++m) sZsq[m * 16 + n16] = zsq[m];

  float bval[4][4]; int bidx[4][4];
  #pragma unroll
  for (int m = 0; m < 4; ++m)
    #pragma unroll
    for (int r = 0; r < 4; ++r) { bval[m][r] = FLT_MAX; bidx[m][r] = 0; }

  const half8* __restrict__ bhp = (const half8*)(ws + WS_EHI);
  const half8* __restrict__ blp = (const half8*)(ws + WS_ELO);
  const float* __restrict__ esq = ws + WS_ESQH;
  const size_t rbase = (size_t)wave * 16384 + n16 * 4 + quad;  // half8 units

  half8 pb[2][4]; float peh[2];
  {
    pb[0][0] = bhp[rbase];  pb[0][1] = bhp[rbase + 64];
    pb[0][2] = blp[rbase];  pb[0][3] = blp[rbase + 64];
    peh[0] = esq[wbase + n16];
  }

  for (int g = 0; g < 128; ++g) {           // 128 groups of 16 codes
    const int cur = g & 1, nxt = cur ^ 1;
    if (g < 127) {                          // prefetch next group (no barriers)
      size_t rb = rbase + (size_t)(g + 1) * 128;
      pb[nxt][0] = bhp[rb];  pb[nxt][1] = bhp[rb + 64];
      pb[nxt][2] = blp[rb];  pb[nxt][3] = blp[rb + 64];
      peh[nxt] = esq[wbase + (g + 1) * 16 + n16];
    }
    floatx4 acc[4];
    #pragma unroll
    for (int m = 0; m < 4; ++m) acc[m] = (floatx4){0.f, 0.f, 0.f, 0.f};
    // 3 terms x 2 k-chunks; m-interleaved for 4 independent chains
    #pragma unroll
    for (int m = 0; m < 4; ++m) acc[m] = __builtin_amdgcn_mfma_f32_16x16x32_f16(ahi[m][0], pb[cur][0], acc[m], 0, 0, 0);
    #pragma unroll
    for (int m = 0; m < 4; ++m) acc[m] = __builtin_amdgcn_mfma_f32_16x16x32_f16(ahi[m][1], pb[cur][1], acc[m], 0, 0, 0);
    #pragma unroll
    for (int m = 0; m < 4; ++m) acc[m] = __builtin_amdgcn_mfma_f32_16x16x32_f16(ahi[m][0], pb[cur][2], acc[m], 0, 0, 0);
    #pragma unroll
    for (int m = 0; m < 4; ++m) acc[m] = __builtin_amdgcn_mfma_f32_16x16x32_f16(ahi[m][1], pb[cur][3], acc[m], 0, 0, 0);
    #pragma unroll
    for (int m = 0; m < 4; ++m) acc[m] = __builtin_amdgcn_mfma_f32_16x16x32_f16(alo[m][0], pb[cur][0], acc[m], 0, 0, 0);
    #pragma unroll
    for (int m = 0; m < 4; ++m) acc[m] = __builtin_amdgcn_mfma_f32_16x16x32_f16(alo[m][1], pb[cur][1], acc[m], 0, 0, 0);

    const int code = wbase + g * 16 + n16;  // C layout: col(lane&15)=code
    const float e2 = peh[cur];
    #pragma unroll
    for (int m = 0; m < 4; ++m)
      #pragma unroll
      for (int r = 0; r < 4; ++r) {
        float tv = e2 - acc[m][r];
        if (tv < bval[m][r]) { bval[m][r] = tv; bidx[m][r] = code; }
      }
  }

  // ---- per-wave argmin reduce across n16 lanes (tie -> smaller index)
  #pragma unroll
  for (int m = 0; m < 4; ++m)
    #pragma unroll
    for (int r = 0; r < 4; ++r) {
      float v = bval[m][r]; int i = bidx[m][r];
      #pragma unroll
      for (int off = 1; off < 16; off <<= 1) {
        float ov = __shfl_xor(v, off);
        int   oi = __shfl_xor(i, off);
        if (ov < v || (ov == v && oi < i)) { v = ov; i = oi; }
      }
      if (n16 == 0) {
        int vox = m * 16 + quad * 4 + r;    // C layout: row = quad*4 + r
        sMval[wave][vox] = v; sMidx[wave][vox] = i;
      }
    }
  __syncthreads();

  // ---- cross-wave merge (waves hold ascending code ranges), loss, indices
  if (tid < 64) {                           // wave 0 entirely
    float best = sMval[0][tid]; int bi = sMidx[0][tid];
    #pragma unroll
    for (int w = 1; w < 4; ++w) {
      float ov = sMval[w][tid]; int oi = sMidx[w][tid];
      if (ov < best || (ov == best && oi < bi)) { best = ov; bi = oi; }
    }
    out[IDX_OFF + vb + tid] = (float)bi;
    sIdxF[tid] = bi;
    float d2 = sZsq[tid] + 2.0f * best;     // exact: z_sq - 2dot + e_sq
    #pragma unroll
    for (int off = 1; off < 64; off <<= 1) d2 += __shfl_xor(d2, off);
    if (tid == 0) atomicAdd(ws + WS_ACC, d2);
  }
  __syncthreads();

  // ---- gather quantized rows (fp32 originals)
  for (int i = tid; i < 1024; i += 256) {   // 64 rows x 16 float4 chunks
    int v = i >> 4, c = i & 15;
    int idx = sIdxF[v];
    float4 q = *(const float4*)(e + (size_t)idx * DIM + c * 4);
    *(float4*)(out + Q_OFF + (size_t)(vb + v) * DIM + c * 4) = q;
  }

  // ---- last block writes the two loss scalars
  __threadfence();
  if (tid == 0) {
    int old = atomicAdd((int*)ws + WS_CNT, 1);
    if (old == (int)gridDim.x - 1) {
      __threadfence();
      float s = atomicAdd(ws + WS_ACC, 0.0f);   // coherent read of final sum
      float m = s * (1.0f / (float)(N_VOX * DIM));
      out[VQ_OFF] = m;
      out[CM_OFF] = m;
    }
  }
}

// ----------------------------------------------------------------
extern "C" void kernel_launch(void* const* d_in, const int* in_sizes, int n_in,
                              void* d_out, int out_size, void* d_ws, size_t ws_size,
                              hipStream_t stream) {
  const float* z = (const float*)d_in[0];
  const float* e = (const float*)d_in[1];
  float* out = (float*)d_out;
  float* ws = (float*)d_ws;

  k_cvt<<<(N_CODES * 8) / 256, 256, 0, stream>>>(e, ws);
  k_argmin<<<N_VOX / 64, 256, 0, stream>>>(z, e, ws, out);
}

// Round 4
// 210.121 us; speedup vs baseline: 19.6645x; 19.6645x over previous
//
#include <hip/hip_runtime.h>
#include <float.h>

#define N_VOX 32768
#define N_CODES 8192
#define DIM 64

// output float offsets (flat, in return order)
#define Q_OFF 0
#define VQ_OFF (N_VOX * DIM)      // 2097152
#define CM_OFF (VQ_OFF + 1)
#define IDX_OFF (VQ_OFF + 2)

// workspace float offsets
#define WS_ACC 0                      // float loss accumulator
#define WS_CNT 1                      // int completion counter
#define WS_ESQH 64                    // 8192 floats: ||e||^2 / 2
#define WS_EHI (WS_ESQH + N_CODES)    // hi-plane f16, fragment-ordered (1 MB)
#define WS_ELO (WS_EHI + N_CODES * DIM / 2)   // lo-plane f16 (1 MB)

typedef _Float16 half8 __attribute__((ext_vector_type(8)));
typedef float floatx4 __attribute__((ext_vector_type(4)));

// ---------------------------------------------------------------- k_cvt
// Codebook -> hi/lo f16 planes stored in MFMA B-fragment order:
// half8 index = g*128 + kc*64 + n*4 + q   (g=row>>4, n=row&15, kc,q from chunk)
// so a wave's frag load (lane=(q,n)) is one contiguous, coalesced 1 KB.
__global__ __launch_bounds__(256) void k_cvt(const float* __restrict__ e,
                                             float* __restrict__ ws) {
  int gid = blockIdx.x * 256 + threadIdx.x;
  if (gid == 0) { ws[WS_ACC] = 0.f; ((int*)ws)[WS_CNT] = 0; }
  int row = gid >> 3, c = gid & 7;          // 8 chunks of 8 dims per row
  const float* src = e + (size_t)row * DIM + c * 8;
  float4 a = *(const float4*)src;
  float4 b = *(const float4*)(src + 4);
  float x[8] = {a.x, a.y, a.z, a.w, b.x, b.y, b.z, b.w};
  float s = 0.f;
  half8 hv, lv;
  #pragma unroll
  for (int j = 0; j < 8; ++j) {
    s += x[j] * x[j];                       // esq in fp32 from originals
    _Float16 h = (_Float16)x[j];
    hv[j] = h;
    lv[j] = (_Float16)(x[j] - (float)h);
  }
  s += __shfl_xor(s, 1); s += __shfl_xor(s, 2); s += __shfl_xor(s, 4);
  if (c == 0) ws[WS_ESQH + row] = 0.5f * s;
  int g = row >> 4, n = row & 15, kc = c >> 2, q = c & 3;
  size_t p = (size_t)g * 128 + kc * 64 + n * 4 + q;
  ((half8*)(ws + WS_EHI))[p] = hv;
  ((half8*)(ws + WS_ELO))[p] = lv;
}

// ---------------------------------------------------------------- k_argmin
// Block = 64 voxels, 4 waves; each wave: same 64 voxels (4 m-frags in regs)
// x its own 2048-code quarter. No LDS staging / no barriers in the K-loop:
// B-frags stream from L2-resident planes. Double-buffer is EXPLICIT named
// registers with a manually unrolled-by-2 loop (R3's pb[cur] dynamic index
// spilled to scratch: WRITE_SIZE 128KB->8.4MB, 21x regression).
// Surrogate t = esq/2 - dot; 3-term split MFMA (hh + hl + lh).
__global__ __launch_bounds__(256, 2) void k_argmin(const float* __restrict__ z,
                                                   const float* __restrict__ e,
                                                   float* __restrict__ ws,
                                                   float* __restrict__ out) {
  __shared__ float sMval[4][64];
  __shared__ int   sMidx[4][64];
  __shared__ float sZsq[64];
  __shared__ int   sIdxF[64];

  const int tid  = threadIdx.x;
  const int lane = tid & 63;
  const int wave = tid >> 6;
  const int n16  = lane & 15;
  const int quad = lane >> 4;
  const int vb   = blockIdx.x * 64;
  const int wbase = wave * 2048;            // this wave's code range

  // ---- A fragments (4 m-frags x 2 k-chunks, hi/lo) + z_sq
  half8 ahi[4][2], alo[4][2];
  float zsq[4] = {0.f, 0.f, 0.f, 0.f};
  #pragma unroll
  for (int m = 0; m < 4; ++m)
    #pragma unroll
    for (int kc = 0; kc < 2; ++kc) {
      const float* src = z + (size_t)(vb + m * 16 + n16) * DIM + kc * 32 + quad * 8;
      float4 a = *(const float4*)src;
      float4 b = *(const float4*)(src + 4);
      float x[8] = {a.x, a.y, a.z, a.w, b.x, b.y, b.z, b.w};
      #pragma unroll
      for (int j = 0; j < 8; ++j) {
        zsq[m] += x[j] * x[j];
        _Float16 h = (_Float16)x[j];
        ahi[m][kc][j] = h;
        alo[m][kc][j] = (_Float16)(x[j] - (float)h);
      }
    }
  #pragma unroll
  for (int m = 0; m < 4; ++m) {             // reduce over quads (lanes ^16,^32)
    zsq[m] += __shfl_xor(zsq[m], 16);
    zsq[m] += __shfl_xor(zsq[m], 32);
  }
  if (wave == 0 && quad == 0)
    #pragma unroll
    for (int m = 0; m < 4; ++m) sZsq[m * 16 + n16] = zsq[m];

  float bval[4][4]; int bidx[4][4];
  #pragma unroll
  for (int m = 0; m < 4; ++m)
    #pragma unroll
    for (int r = 0; r < 4; ++r) { bval[m][r] = FLT_MAX; bidx[m][r] = 0; }

  const half8* __restrict__ bhp = (const half8*)(ws + WS_EHI);
  const half8* __restrict__ blp = (const half8*)(ws + WS_ELO);
  const float* __restrict__ esq = ws + WS_ESQH;
  const size_t rbase = (size_t)wave * 16384 + n16 * 4 + quad;  // half8 units

  // one 16-code group: 24 MFMAs + argmin update (all indices compile-time)
  auto step = [&](half8 b0, half8 b1, half8 b2, half8 b3, float e2, int codebase) {
    floatx4 acc[4];
    #pragma unroll
    for (int m = 0; m < 4; ++m) acc[m] = (floatx4){0.f, 0.f, 0.f, 0.f};
    #pragma unroll
    for (int m = 0; m < 4; ++m) acc[m] = __builtin_amdgcn_mfma_f32_16x16x32_f16(ahi[m][0], b0, acc[m], 0, 0, 0);
    #pragma unroll
    for (int m = 0; m < 4; ++m) acc[m] = __builtin_amdgcn_mfma_f32_16x16x32_f16(ahi[m][1], b1, acc[m], 0, 0, 0);
    #pragma unroll
    for (int m = 0; m < 4; ++m) acc[m] = __builtin_amdgcn_mfma_f32_16x16x32_f16(ahi[m][0], b2, acc[m], 0, 0, 0);
    #pragma unroll
    for (int m = 0; m < 4; ++m) acc[m] = __builtin_amdgcn_mfma_f32_16x16x32_f16(ahi[m][1], b3, acc[m], 0, 0, 0);
    #pragma unroll
    for (int m = 0; m < 4; ++m) acc[m] = __builtin_amdgcn_mfma_f32_16x16x32_f16(alo[m][0], b0, acc[m], 0, 0, 0);
    #pragma unroll
    for (int m = 0; m < 4; ++m) acc[m] = __builtin_amdgcn_mfma_f32_16x16x32_f16(alo[m][1], b1, acc[m], 0, 0, 0);
    const int code = codebase + n16;        // C layout: col(lane&15)=code
    #pragma unroll
    for (int m = 0; m < 4; ++m)
      #pragma unroll
      for (int r = 0; r < 4; ++r) {
        float tv = e2 - acc[m][r];
        if (tv < bval[m][r]) { bval[m][r] = tv; bidx[m][r] = code; }
      }
  };

  // explicit ping-pong registers, manual unroll-by-2 (NO dynamic indexing)
  half8 pa0 = bhp[rbase], pa1 = bhp[rbase + 64];
  half8 pa2 = blp[rbase], pa3 = blp[rbase + 64];
  float pae = esq[wbase + n16];
  half8 pb0, pb1, pb2, pb3; float pbe;

  for (int g = 0; g < 128; g += 2) {
    {                                        // prefetch group g+1 (always exists)
      size_t rb = rbase + (size_t)(g + 1) * 128;
      pb0 = bhp[rb];  pb1 = bhp[rb + 64];
      pb2 = blp[rb];  pb3 = blp[rb + 64];
      pbe = esq[wbase + (g + 1) * 16 + n16];
    }
    step(pa0, pa1, pa2, pa3, pae, wbase + g * 16);
    if (g + 2 < 128) {                       // prefetch group g+2
      size_t rb = rbase + (size_t)(g + 2) * 128;
      pa0 = bhp[rb];  pa1 = bhp[rb + 64];
      pa2 = blp[rb];  pa3 = blp[rb + 64];
      pae = esq[wbase + (g + 2) * 16 + n16];
    }
    step(pb0, pb1, pb2, pb3, pbe, wbase + (g + 1) * 16);
  }

  // ---- per-wave argmin reduce across n16 lanes (tie -> smaller index)
  #pragma unroll
  for (int m = 0; m < 4; ++m)
    #pragma unroll
    for (int r = 0; r < 4; ++r) {
      float v = bval[m][r]; int i = bidx[m][r];
      #pragma unroll
      for (int off = 1; off < 16; off <<= 1) {
        float ov = __shfl_xor(v, off);
        int   oi = __shfl_xor(i, off);
        if (ov < v || (ov == v && oi < i)) { v = ov; i = oi; }
      }
      if (n16 == 0) {
        int vox = m * 16 + quad * 4 + r;    // C layout: row = quad*4 + r
        sMval[wave][vox] = v; sMidx[wave][vox] = i;
      }
    }
  __syncthreads();

  // ---- cross-wave merge (waves hold ascending code ranges), loss, indices
  if (tid < 64) {                           // wave 0 entirely
    float best = sMval[0][tid]; int bi = sMidx[0][tid];
    #pragma unroll
    for (int w = 1; w < 4; ++w) {
      float ov = sMval[w][tid]; int oi = sMidx[w][tid];
      if (ov < best || (ov == best && oi < bi)) { best = ov; bi = oi; }
    }
    out[IDX_OFF + vb + tid] = (float)bi;
    sIdxF[tid] = bi;
    float d2 = sZsq[tid] + 2.0f * best;     // exact: z_sq - 2dot + e_sq
    #pragma unroll
    for (int off = 1; off < 64; off <<= 1) d2 += __shfl_xor(d2, off);
    if (tid == 0) atomicAdd(ws + WS_ACC, d2);
  }
  __syncthreads();

  // ---- gather quantized rows (fp32 originals)
  for (int i = tid; i < 1024; i += 256) {   // 64 rows x 16 float4 chunks
    int v = i >> 4, c = i & 15;
    int idx = sIdxF[v];
    float4 q = *(const float4*)(e + (size_t)idx * DIM + c * 4);
    *(float4*)(out + Q_OFF + (size_t)(vb + v) * DIM + c * 4) = q;
  }

  // ---- last block writes the two loss scalars
  __threadfence();
  if (tid == 0) {
    int old = atomicAdd((int*)ws + WS_CNT, 1);
    if (old == (int)gridDim.x - 1) {
      __threadfence();
      float s = atomicAdd(ws + WS_ACC, 0.0f);   // coherent read of final sum
      float m = s * (1.0f / (float)(N_VOX * DIM));
      out[VQ_OFF] = m;
      out[CM_OFF] = m;
    }
  }
}

// ----------------------------------------------------------------
extern "C" void kernel_launch(void* const* d_in, const int* in_sizes, int n_in,
                              void* d_out, int out_size, void* d_ws, size_t ws_size,
                              hipStream_t stream) {
  const float* z = (const float*)d_in[0];
  const float* e = (const float*)d_in[1];
  float* out = (float*)d_out;
  float* ws = (float*)d_ws;

  k_cvt<<<(N_CODES * 8) / 256, 256, 0, stream>>>(e, ws);
  k_argmin<<<N_VOX / 64, 256, 0, stream>>>(z, e, ws, out);
}